// Round 2
// baseline (170.079 us; speedup 1.0000x reference)
//
#include <hip/hip_runtime.h>
#include <stdint.h>

// SelfAttention1D: B=8, C=256, L=2048, D=32, fp32 in/out, bf16 MFMA compute.
//
// ws layout (bytes):
//   Wh  @ 0x000000 : bf16 [320][256]  (rows 0-31 Wq, 32-63 Wk, 64-319 Wv)
//   Qh  @ 0x040000 : bf16 [B][L][32]  Q pre-scaled by (1/sqrt(D))*log2(e)
//   Kth @ 0x140000 : bf16 [B][L][32]  K^T  (j-major, d contiguous)
//   Vh  @ 0x240000 : bf16 [B][256][L] V    (natural layout, j contiguous)
// total 10.25 MB

#define BB 8
#define CC 256
#define LL 2048
#define DD 32

typedef unsigned short u16;
typedef __attribute__((ext_vector_type(8))) short short8;
typedef __attribute__((ext_vector_type(4))) float f32x4;

#define SCALE_LOG2E 0.2550348612f

static __device__ __forceinline__ uint32_t pack2bf16(float hi, float lo) {
    return (__float_as_uint(hi) & 0xFFFF0000u) | (__float_as_uint(lo) >> 16);
}

static __device__ __forceinline__ float fexp2(float v) {
#if __has_builtin(__builtin_amdgcn_exp2f)
    return __builtin_amdgcn_exp2f(v);
#else
    return exp2f(v);
#endif
}

static __device__ __forceinline__ float frcp(float v) {
#if __has_builtin(__builtin_amdgcn_rcpf)
    return __builtin_amdgcn_rcpf(v);
#else
    return 1.0f / v;
#endif
}

// ---------------- kernel 1: W -> bf16 ----------------
__global__ __launch_bounds__(256) void prep_w_kernel(
    const float* __restrict__ Wq, const float* __restrict__ Wk,
    const float* __restrict__ Wv, u16* __restrict__ Wh)
{
    int idx = blockIdx.x * 256 + threadIdx.x;     // 320 rows * 64 float4
    int r = idx >> 6;
    int c4 = (idx & 63) << 2;
    const float* src;
    if (r < 32)       src = Wq + (size_t)r * CC + c4;
    else if (r < 64)  src = Wk + (size_t)(r - 32) * CC + c4;
    else              src = Wv + (size_t)(r - 64) * CC + c4;
    float4 v = *(const float4*)src;
    uint2 o;
    o.x = pack2bf16(v.y, v.x);
    o.y = pack2bf16(v.w, v.z);
    *(uint2*)(Wh + (size_t)r * CC + c4) = o;
}

// ---------------- kernel 2: QKV projection ----------------
// grid 256 = (b = blk&7) x (l-tile 64). 1024 threads = 16 waves.
// Stage x[256 c][64 l] fp32 in LDS (coalesced float4), then wave (wl,wm):
// l-subtile wl*16, m-tiles wm*5..+4, B-frags from LDS, A-frags from Wh.
__global__ __launch_bounds__(1024, 4) void proj_kernel(
    const float* __restrict__ x, const u16* __restrict__ Wh,
    const float* __restrict__ bq, const float* __restrict__ bk,
    const float* __restrict__ bv,
    u16* __restrict__ Qh, u16* __restrict__ Kth, u16* __restrict__ Vh)
{
    __shared__ float xs[256 * 68];          // stride 68 fp32 (16B-aligned rows)
    const int blk = blockIdx.x;
    const int b = blk & 7;
    const int l0 = (blk >> 3) << 6;
    const int tid = threadIdx.x;
    const int w = tid >> 6;
    const int lane = tid & 63;
    const int ln = lane & 15;
    const int q = lane >> 4;

    // stage: wave w covers c rows w*16..w*16+15
    const float* xb = x + (size_t)b * CC * LL + l0;
#pragma unroll
    for (int rr = 0; rr < 4; ++rr) {
        const int c = w * 16 + rr * 4 + q;
        const int l4 = ln * 4;
        *(float4*)&xs[c * 68 + l4] = *(const float4*)(xb + (size_t)c * LL + l4);
    }
    __syncthreads();

    const int wl = w & 3;
    const int wm = w >> 2;
    const int lcol = l0 + wl * 16 + ln;

    f32x4 acc[5];
#pragma unroll
    for (int i = 0; i < 5; ++i) acc[i] = (f32x4){0.f, 0.f, 0.f, 0.f};

    for (int c0 = 0; c0 < CC; c0 += 32) {
        float f[8];
#pragma unroll
        for (int e = 0; e < 8; ++e) f[e] = xs[(c0 + q * 8 + e) * 68 + wl * 16 + ln];
        union { uint32_t u[4]; short8 s; } bf;
#pragma unroll
        for (int d = 0; d < 4; ++d) bf.u[d] = pack2bf16(f[2 * d + 1], f[2 * d]);

#pragma unroll
        for (int mi = 0; mi < 5; ++mi) {
            const int mt = wm * 5 + mi;
            const short8 af = *(const short8*)(Wh + (size_t)(mt * 16 + ln) * CC + c0 + q * 8);
            acc[mi] = __builtin_amdgcn_mfma_f32_16x16x32_bf16(af, bf.s, acc[mi], 0, 0, 0);
        }
    }

#pragma unroll
    for (int mi = 0; mi < 5; ++mi) {
        const int mt = wm * 5 + mi;
        const int tbase = mt * 16;
        const int rq = tbase + q * 4;
        if (tbase < 32) {            // Q rows, pre-scaled
            float v0 = (acc[mi][0] + bq[rq + 0]) * SCALE_LOG2E;
            float v1 = (acc[mi][1] + bq[rq + 1]) * SCALE_LOG2E;
            float v2 = (acc[mi][2] + bq[rq + 2]) * SCALE_LOG2E;
            float v3 = (acc[mi][3] + bq[rq + 3]) * SCALE_LOG2E;
            uint2 o; o.x = pack2bf16(v1, v0); o.y = pack2bf16(v3, v2);
            *(uint2*)(Qh + (size_t)(b * LL + lcol) * DD + rq) = o;
        } else if (tbase < 64) {     // K rows
            const int rk = rq - 32;
            float v0 = acc[mi][0] + bk[rk + 0];
            float v1 = acc[mi][1] + bk[rk + 1];
            float v2 = acc[mi][2] + bk[rk + 2];
            float v3 = acc[mi][3] + bk[rk + 3];
            uint2 o; o.x = pack2bf16(v1, v0); o.y = pack2bf16(v3, v2);
            *(uint2*)(Kth + (size_t)(b * LL + lcol) * DD + rk) = o;
        } else {                     // V rows -> Vh[b][c][l]
            const int cv = rq - 64;
#pragma unroll
            for (int rr = 0; rr < 4; ++rr) {
                float v = acc[mi][rr] + bv[cv + rr];
                Vh[(size_t)(b * CC + cv + rr) * LL + lcol] = (u16)(__float_as_uint(v) >> 16);
            }
        }
    }
}

// ---------------- kernel 3: fused attention ----------------
// grid 256 = (b = blk&7) x (i-tile 64). 1024 threads = 16 waves:
// wc = w>>2 (c-slice 64), wj = (w>>1)&1 (j-half 1024), wi = w&1 (i-half 32).
// Only wc==0 waves (one per SIMD) compute S^T = K·Q^T + exp2 for their
// (wj,wi) slice, publishing P^T through double-buffered LDS; all 16 waves
// consume P for O^T += V·P^T. Partial O over wj reduced in LDS, l via
// ones-MFMA; cooperative coalesced finalize.
__global__ __launch_bounds__(1024, 4) void attn_kernel(
    const u16* __restrict__ Qh, const u16* __restrict__ Kth,
    const u16* __restrict__ Vh, const float* __restrict__ x,
    const float* __restrict__ gamma, float* __restrict__ out)
{
    __shared__ u16 pbuf[2 * 4 * 32 * 40];   // [dbl][wj*2+wi][i-row 32][40] (20.5 KB)
    __shared__ float obuf[256 * 68];        // [c 256][i 64] stride 68 (69.6 KB)
    __shared__ float lbuf[2 * 64];          // [wj][i]

    const int blk = blockIdx.x;
    const int b = blk & 7;
    const int i0 = (blk >> 3) << 6;
    const int tid = threadIdx.x;
    const int w = tid >> 6;
    const int lane = tid & 63;
    const int ln = lane & 15;
    const int q = lane >> 4;
    const int wc = w >> 2;
    const int wj = (w >> 1) & 1;
    const int wi = w & 1;
    const bool is_s = (wc == 0);

    const u16* Kb = Kth + (size_t)b * LL * DD;
    const u16* Vb = Vh + ((size_t)b * CC + wc * 64) * LL;
    const int jbase = wj * 1024;
    const int pslot = (wj * 2 + wi) * 32 * 40;

    short8 qf[2];
    if (is_s) {
#pragma unroll
        for (int nt = 0; nt < 2; ++nt)
            qf[nt] = *(const short8*)(Qh + ((size_t)(b * LL) + i0 + wi * 32 + nt * 16 + ln) * DD + q * 8);
    }

    union { uint32_t u[4]; short8 s; } onesu;
    onesu.u[0] = onesu.u[1] = onesu.u[2] = onesu.u[3] = 0x3F803F80u;  // bf16 1.0 x8
    const short8 ones = onesu.s;
    const f32x4 zf = {0.f, 0.f, 0.f, 0.f};

    f32x4 oacc[4][2];
#pragma unroll
    for (int a = 0; a < 4; ++a)
#pragma unroll
        for (int c = 0; c < 2; ++c) oacc[a][c] = zf;
    f32x4 lacc[2];
    lacc[0] = zf; lacc[1] = zf;

    // prologue: S(it=0) -> buf 0
    if (is_s) {
        u16* pw = pbuf + pslot;
#pragma unroll
        for (int mt = 0; mt < 2; ++mt) {
            const short8 kf = *(const short8*)(Kb + ((size_t)(jbase + mt * 16 + ln)) * DD + q * 8);
#pragma unroll
            for (int nt = 0; nt < 2; ++nt) {
                const f32x4 st = __builtin_amdgcn_mfma_f32_16x16x32_bf16(kf, qf[nt], zf, 0, 0, 0);
                const float e0 = fexp2(st[0]), e1 = fexp2(st[1]);
                const float e2 = fexp2(st[2]), e3 = fexp2(st[3]);
                uint2 d; d.x = pack2bf16(e1, e0); d.y = pack2bf16(e3, e2);
                *(uint2*)(pw + (nt * 16 + ln) * 40 + mt * 16 + q * 4) = d;
            }
        }
    }
    short8 vf[4];
#pragma unroll
    for (int mt = 0; mt < 4; ++mt)
        vf[mt] = *(const short8*)(Vb + (size_t)(mt * 16 + ln) * LL + jbase + q * 8);
    __syncthreads();

    for (int it = 0; it < 32; ++it) {
        const int cur = it & 1;
        const int jn = jbase + ((it + 1) & 31) * 32;
        // prefetch V(it+1)
        short8 vn[4];
#pragma unroll
        for (int mt = 0; mt < 4; ++mt)
            vn[mt] = *(const short8*)(Vb + (size_t)(mt * 16 + ln) * LL + jn + q * 8);
        // prefetch K(it+1) (S-waves)
        short8 kn[2];
        if (is_s && (it + 1 < 32)) {
#pragma unroll
            for (int mt = 0; mt < 2; ++mt)
                kn[mt] = *(const short8*)(Kb + ((size_t)(jn + mt * 16 + ln)) * DD + q * 8);
        }
        // consume P(it)
        const u16* pr = pbuf + cur * (4 * 32 * 40) + pslot;
        short8 pf[2];
#pragma unroll
        for (int nt = 0; nt < 2; ++nt)
            pf[nt] = *(const short8*)(pr + (nt * 16 + ln) * 40 + q * 8);
#pragma unroll
        for (int mt = 0; mt < 4; ++mt)
#pragma unroll
            for (int nt = 0; nt < 2; ++nt)
                oacc[mt][nt] = __builtin_amdgcn_mfma_f32_16x16x32_bf16(vf[mt], pf[nt], oacc[mt][nt], 0, 0, 0);
        if (is_s) {
#pragma unroll
            for (int nt = 0; nt < 2; ++nt)
                lacc[nt] = __builtin_amdgcn_mfma_f32_16x16x32_bf16(ones, pf[nt], lacc[nt], 0, 0, 0);
            // produce P(it+1) -> other buffer
            if (it + 1 < 32) {
                u16* pw = pbuf + (1 - cur) * (4 * 32 * 40) + pslot;
#pragma unroll
                for (int mt = 0; mt < 2; ++mt) {
#pragma unroll
                    for (int nt = 0; nt < 2; ++nt) {
                        const f32x4 st = __builtin_amdgcn_mfma_f32_16x16x32_bf16(kn[mt], qf[nt], zf, 0, 0, 0);
                        const float e0 = fexp2(st[0]), e1 = fexp2(st[1]);
                        const float e2 = fexp2(st[2]), e3 = fexp2(st[3]);
                        uint2 d; d.x = pack2bf16(e1, e0); d.y = pack2bf16(e3, e2);
                        *(uint2*)(pw + (nt * 16 + ln) * 40 + mt * 16 + q * 4) = d;
                    }
                }
            }
        }
#pragma unroll
        for (int mt = 0; mt < 4; ++mt) vf[mt] = vn[mt];
        __syncthreads();
    }

    // l partials (any q holds the same value; q==0 writes)
    if (is_s && q == 0) {
#pragma unroll
        for (int nt = 0; nt < 2; ++nt)
            lbuf[wj * 64 + wi * 32 + nt * 16 + ln] = lacc[nt][0];
    }
    // O reduction over wj
    if (wj == 0) {
#pragma unroll
        for (int mt = 0; mt < 4; ++mt)
#pragma unroll
            for (int nt = 0; nt < 2; ++nt)
#pragma unroll
                for (int r = 0; r < 4; ++r)
                    obuf[(wc * 64 + mt * 16 + q * 4 + r) * 68 + wi * 32 + nt * 16 + ln] = oacc[mt][nt][r];
    }
    __syncthreads();
    if (wj == 1) {
#pragma unroll
        for (int mt = 0; mt < 4; ++mt)
#pragma unroll
            for (int nt = 0; nt < 2; ++nt)
#pragma unroll
                for (int r = 0; r < 4; ++r)
                    obuf[(wc * 64 + mt * 16 + q * 4 + r) * 68 + wi * 32 + nt * 16 + ln] += oacc[mt][nt][r];
    }
    __syncthreads();

    // finalize: out = gamma * O/l + x, fully coalesced float4
    const float g = gamma[0];
    const int il = (tid & 15) * 4;
    const float4 la = *(const float4*)&lbuf[il];
    const float4 lb2 = *(const float4*)&lbuf[64 + il];
    float4 li;
    li.x = frcp(la.x + lb2.x); li.y = frcp(la.y + lb2.y);
    li.z = frcp(la.z + lb2.z); li.w = frcp(la.w + lb2.w);
#pragma unroll
    for (int rr = 0; rr < 4; ++rr) {
        const int c = (tid >> 4) + rr * 64;
        const float4 ov = *(const float4*)&obuf[c * 68 + il];
        const size_t idx = ((size_t)b * CC + c) * LL + i0 + il;
        const float4 xv = *(const float4*)(x + idx);
        float4 o;
        o.x = g * (ov.x * li.x) + xv.x;
        o.y = g * (ov.y * li.y) + xv.y;
        o.z = g * (ov.z * li.z) + xv.z;
        o.w = g * (ov.w * li.w) + xv.w;
        *(float4*)(out + idx) = o;
    }
}

// ---------------- launcher ----------------
extern "C" void kernel_launch(void* const* d_in, const int* in_sizes, int n_in,
                              void* d_out, int out_size, void* d_ws, size_t ws_size,
                              hipStream_t stream)
{
    const float* x     = (const float*)d_in[0];
    const float* Wq    = (const float*)d_in[1];
    const float* bq    = (const float*)d_in[2];
    const float* Wk    = (const float*)d_in[3];
    const float* bk    = (const float*)d_in[4];
    const float* Wv    = (const float*)d_in[5];
    const float* bv    = (const float*)d_in[6];
    const float* gamma = (const float*)d_in[7];
    float* out = (float*)d_out;

    uint8_t* ws = (uint8_t*)d_ws;
    u16* Wh  = (u16*)(ws + 0x000000);
    u16* Qh  = (u16*)(ws + 0x040000);
    u16* Kth = (u16*)(ws + 0x140000);
    u16* Vh  = (u16*)(ws + 0x240000);

    prep_w_kernel<<<80, 256, 0, stream>>>(Wq, Wk, Wv, Wh);
    proj_kernel<<<256, 1024, 0, stream>>>(x, Wh, bq, bk, bv, Qh, Kth, Vh);
    attn_kernel<<<256, 1024, 0, stream>>>(Qh, Kth, Vh, x, gamma, out);
}

// Round 3
// 157.399 us; speedup vs baseline: 1.0806x; 1.0806x over previous
//
#include <hip/hip_runtime.h>
#include <stdint.h>

// SelfAttention1D: B=8, C=256, L=2048, D=32, fp32 in/out, bf16 MFMA compute.
//
// ws layout (bytes):
//   Wh  @ 0x000000 : bf16 [320][256]   rows 0-31 Wq, 32-63 Wk, 64-319 Wv (160 KB)
//   xt  @ 0x040000 : bf16 [B][L][C]    x transposed, c-contiguous (8 MB)
//   Qh  @ 0x840000 : bf16 [B][L][32]   Q pre-scaled by (1/sqrt(D))*log2(e) (1 MB)
//   Kth @ 0x940000 : bf16 [B][L][32]   K^T, d-contiguous (1 MB)
//   Vh  @ 0xA40000 : bf16 [B][256][L]  V, j-contiguous (8 MB)
// total ~18.3 MB

#define BB 8
#define CC 256
#define LL 2048
#define DD 32

typedef unsigned short u16;
typedef __attribute__((ext_vector_type(8))) short short8;
typedef __attribute__((ext_vector_type(4))) float f32x4;

#define SCALE_LOG2E 0.2550348612f

static __device__ __forceinline__ uint32_t pack2bf16(float hi, float lo) {
    return (__float_as_uint(hi) & 0xFFFF0000u) | (__float_as_uint(lo) >> 16);
}

static __device__ __forceinline__ float fexp2(float v) {
#if __has_builtin(__builtin_amdgcn_exp2f)
    return __builtin_amdgcn_exp2f(v);
#else
    return exp2f(v);
#endif
}

static __device__ __forceinline__ float frcp(float v) {
#if __has_builtin(__builtin_amdgcn_rcpf)
    return __builtin_amdgcn_rcpf(v);
#else
    return 1.0f / v;
#endif
}

// ---------------- kernel 1: W -> bf16 ----------------
__global__ __launch_bounds__(256) void prep_w_kernel(
    const float* __restrict__ Wq, const float* __restrict__ Wk,
    const float* __restrict__ Wv, u16* __restrict__ Wh)
{
    int idx = blockIdx.x * 256 + threadIdx.x;     // 320 rows * 64 float4
    int r = idx >> 6;
    int c4 = (idx & 63) << 2;
    const float* src;
    if (r < 32)       src = Wq + (size_t)r * CC + c4;
    else if (r < 64)  src = Wk + (size_t)(r - 32) * CC + c4;
    else              src = Wv + (size_t)(r - 64) * CC + c4;
    float4 v = *(const float4*)src;
    uint2 o;
    o.x = pack2bf16(v.y, v.x);
    o.y = pack2bf16(v.w, v.z);
    *(uint2*)(Wh + (size_t)r * CC + c4) = o;
}

// ---------------- kernel 1b: x -> xt[B][L][C] bf16 (transpose) ----------------
// grid 1024 = 8 b x 32 l-tiles(64) x 4 c-tiles(64). LDS 64x64 tile, stride 65
// (odd stride -> 2-way max on both scalar phases; global coalesced both sides).
__global__ __launch_bounds__(256) void prep_xt_kernel(
    const float* __restrict__ x, u16* __restrict__ xt)
{
    __shared__ float xs[64 * 65];
    const int blk = blockIdx.x;
    const int b = blk & 7;
    const int t = blk >> 3;              // 0..127
    const int l0 = (t & 31) << 6;
    const int c0 = (t >> 5) << 6;
    const int tid = threadIdx.x;
    const int ln16 = tid & 15;
    const int r0 = tid >> 4;             // 0..15

    const float* xb = x + ((size_t)(b * CC + c0)) * LL + l0;
#pragma unroll
    for (int rr = 0; rr < 4; ++rr) {
        const int c = r0 + rr * 16;
        const float4 v = *(const float4*)(xb + (size_t)c * LL + ln16 * 4);
        float* d = &xs[c * 65 + ln16 * 4];
        d[0] = v.x; d[1] = v.y; d[2] = v.z; d[3] = v.w;
    }
    __syncthreads();
    u16* xo = xt + ((size_t)(b * LL + l0)) * CC + c0;
    const int c4 = ln16 * 4;
#pragma unroll
    for (int rr = 0; rr < 4; ++rr) {
        const int l = r0 + rr * 16;
        const float f0 = xs[(c4 + 0) * 65 + l];
        const float f1 = xs[(c4 + 1) * 65 + l];
        const float f2 = xs[(c4 + 2) * 65 + l];
        const float f3 = xs[(c4 + 3) * 65 + l];
        uint2 o; o.x = pack2bf16(f1, f0); o.y = pack2bf16(f3, f2);
        *(uint2*)(xo + (size_t)l * CC + c4) = o;
    }
}

// ---------------- kernel 2: QKV projection ----------------
// grid 1024 = 8 b x 64 l-tiles(32) x 2 m-halves(160 rows). 256 thr (4 waves):
// wave (wl = w&1 -> 16 l, wm = w>>1 -> 5 m-tiles). Both frags are 16B-contiguous
// L2 loads (Wh k-contig; xt c-contig). No LDS, no packing in the loop.
__global__ __launch_bounds__(256, 4) void proj_kernel(
    const u16* __restrict__ xt, const u16* __restrict__ Wh,
    const float* __restrict__ bq, const float* __restrict__ bk,
    const float* __restrict__ bv,
    u16* __restrict__ Qh, u16* __restrict__ Kth, u16* __restrict__ Vh)
{
    const int blk = blockIdx.x;
    const int b = blk & 7;
    const int t = blk >> 3;              // 0..127
    const int l0 = (t & 63) << 5;
    const int mh = t >> 6;               // 0..1
    const int tid = threadIdx.x;
    const int w = tid >> 6;
    const int lane = tid & 63;
    const int ln = lane & 15;
    const int q = lane >> 4;
    const int wl = w & 1;
    const int wm = w >> 1;
    const int l = l0 + wl * 16 + ln;
    const u16* xrow = xt + ((size_t)(b * LL) + l) * CC;
    const int mbase = mh * 160 + wm * 80;

    f32x4 acc[5];
#pragma unroll
    for (int i = 0; i < 5; ++i) acc[i] = (f32x4){0.f, 0.f, 0.f, 0.f};

#pragma unroll
    for (int c0 = 0; c0 < CC; c0 += 32) {
        const short8 bf = *(const short8*)(xrow + c0 + q * 8);
#pragma unroll
        for (int mt = 0; mt < 5; ++mt) {
            const short8 af = *(const short8*)(Wh + (size_t)(mbase + mt * 16 + ln) * CC + c0 + q * 8);
            acc[mt] = __builtin_amdgcn_mfma_f32_16x16x32_bf16(af, bf, acc[mt], 0, 0, 0);
        }
    }

#pragma unroll
    for (int mt = 0; mt < 5; ++mt) {
        const int rg = mbase + mt * 16 + q * 4;   // global output row
        if (rg < 32) {                   // Q rows, pre-scaled
            float v0 = (acc[mt][0] + bq[rg + 0]) * SCALE_LOG2E;
            float v1 = (acc[mt][1] + bq[rg + 1]) * SCALE_LOG2E;
            float v2 = (acc[mt][2] + bq[rg + 2]) * SCALE_LOG2E;
            float v3 = (acc[mt][3] + bq[rg + 3]) * SCALE_LOG2E;
            uint2 o; o.x = pack2bf16(v1, v0); o.y = pack2bf16(v3, v2);
            *(uint2*)(Qh + ((size_t)(b * LL) + l) * DD + rg) = o;
        } else if (rg < 64) {            // K rows
            const int rk = rg - 32;
            float v0 = acc[mt][0] + bk[rk + 0];
            float v1 = acc[mt][1] + bk[rk + 1];
            float v2 = acc[mt][2] + bk[rk + 2];
            float v3 = acc[mt][3] + bk[rk + 3];
            uint2 o; o.x = pack2bf16(v1, v0); o.y = pack2bf16(v3, v2);
            *(uint2*)(Kth + ((size_t)(b * LL) + l) * DD + rk) = o;
        } else {                         // V rows -> Vh[b][c][l]
            const int cv = rg - 64;
#pragma unroll
            for (int rr = 0; rr < 4; ++rr) {
                const float v = acc[mt][rr] + bv[cv + rr];
                Vh[((size_t)(b * CC) + cv + rr) * LL + l] = (u16)(__float_as_uint(v) >> 16);
            }
        }
    }
}

// ---------------- kernel 3: fused attention ----------------
// grid 256 = (b = blk&7 -> XCD L2 affinity) x (i-tile 64). 512 thr (8 waves).
// Per 256-j macro-iter (8 total, 2 barriers each):
//   S phase: wave w computes S^T+exp2 for its own 32-j slice (all 64 i),
//            writes P^T[i 64][j 256] bf16 to LDS (stride 264: 16B-aligned rows,
//            b128 reads schedule to the 8-round minimum).
//   PV phase: wave w does O^T += V.P^T for its exclusive 32-c slice (no
//            O-reduction, no V duplication); V frags ping-pong prefetched.
// l = row-sums accumulated in-register during exp, shuffle-reduced over q,
// cross-wave summed via tiny LDS buffer. Exclusive c => direct epilogue.
__global__ __launch_bounds__(512, 2) void attn_kernel(
    const u16* __restrict__ Qh, const u16* __restrict__ Kth,
    const u16* __restrict__ Vh, const float* __restrict__ x,
    const float* __restrict__ gamma, float* __restrict__ out)
{
    __shared__ u16 pbuf[64 * 264];       // 33.8 KB
    __shared__ float lbuf[8 * 64];       // 2 KB

    const int blk = blockIdx.x;
    const int b = blk & 7;
    const int i0 = (blk >> 3) << 6;
    const int tid = threadIdx.x;
    const int w = tid >> 6;              // 0..7
    const int lane = tid & 63;
    const int ln = lane & 15;
    const int q = lane >> 4;

    const u16* Qb = Qh + ((size_t)(b * LL) + i0) * DD;
    const u16* Kb = Kth + (size_t)(b * LL) * DD;
    const u16* Vb = Vh + ((size_t)(b * CC) + w * 32) * LL;

    // Q B-frags persist: B[k=d][n=i]
    short8 qf[4];
#pragma unroll
    for (int it = 0; it < 4; ++it)
        qf[it] = *(const short8*)(Qb + (size_t)(it * 16 + ln) * DD + q * 8);

    const f32x4 zf = {0.f, 0.f, 0.f, 0.f};
    f32x4 oacc[2][4];                    // [ct][it]
#pragma unroll
    for (int a = 0; a < 2; ++a)
#pragma unroll
        for (int c = 0; c < 4; ++c) oacc[a][c] = zf;
    float lsum[4] = {0.f, 0.f, 0.f, 0.f};

    for (int jm = 0; jm < 8; ++jm) {
        const int j0 = jm * 256;
        const int js = j0 + w * 32;      // this wave's S j-slice

        // ---- S phase: S^T = K.Q^T for 32 j x 64 i, P -> LDS ----
#pragma unroll
        for (int jt = 0; jt < 2; ++jt) {
            const short8 kf = *(const short8*)(Kb + (size_t)(js + jt * 16 + ln) * DD + q * 8);
#pragma unroll
            for (int it = 0; it < 4; ++it) {
                const f32x4 st = __builtin_amdgcn_mfma_f32_16x16x32_bf16(kf, qf[it], zf, 0, 0, 0);
                const float e0 = fexp2(st[0]), e1 = fexp2(st[1]);
                const float e2 = fexp2(st[2]), e3 = fexp2(st[3]);
                lsum[it] += (e0 + e1) + (e2 + e3);
                uint2 d; d.x = pack2bf16(e1, e0); d.y = pack2bf16(e3, e2);
                // P^T row i = it*16+ln, cols j-j0 = w*32 + jt*16 + q*4 ..+3
                *(uint2*)(&pbuf[(it * 16 + ln) * 264 + w * 32 + jt * 16 + q * 4]) = d;
            }
        }
        __syncthreads();

        // ---- PV phase: O^T += V.P^T over this wave's 32 c, 256 j ----
        short8 vf0 = *(const short8*)(Vb + (size_t)(ln) * LL + j0 + q * 8);
        short8 vf1 = *(const short8*)(Vb + (size_t)(16 + ln) * LL + j0 + q * 8);
#pragma unroll
        for (int k = 0; k < 8; ++k) {
            const int kn = ((k + 1) & 7) * 32;
            const short8 vn0 = *(const short8*)(Vb + (size_t)(ln) * LL + j0 + kn + q * 8);
            const short8 vn1 = *(const short8*)(Vb + (size_t)(16 + ln) * LL + j0 + kn + q * 8);
#pragma unroll
            for (int it = 0; it < 4; ++it) {
                const short8 pf = *(const short8*)(&pbuf[(it * 16 + ln) * 264 + k * 32 + q * 8]);
                oacc[0][it] = __builtin_amdgcn_mfma_f32_16x16x32_bf16(vf0, pf, oacc[0][it], 0, 0, 0);
                oacc[1][it] = __builtin_amdgcn_mfma_f32_16x16x32_bf16(vf1, pf, oacc[1][it], 0, 0, 0);
            }
            vf0 = vn0; vf1 = vn1;
        }
        __syncthreads();
    }

    // ---- l reduction: over q (shuffle), then over waves (LDS) ----
#pragma unroll
    for (int it = 0; it < 4; ++it) {
        float s = lsum[it];
        s += __shfl_xor(s, 16);
        s += __shfl_xor(s, 32);
        lsum[it] = s;
    }
    if (q == 0) {
#pragma unroll
        for (int it = 0; it < 4; ++it) lbuf[w * 64 + it * 16 + ln] = lsum[it];
    }
    __syncthreads();

    const float g = gamma[0];
    float linv[4];
#pragma unroll
    for (int it = 0; it < 4; ++it) {
        float s = 0.f;
#pragma unroll
        for (int ww = 0; ww < 8; ++ww) s += lbuf[ww * 64 + it * 16 + ln];
        linv[it] = frcp(s);
    }

    // ---- epilogue: out = gamma*O/l + x (exclusive c rows; 64B segments) ----
#pragma unroll
    for (int ct = 0; ct < 2; ++ct) {
        const int c = w * 32 + ct * 16 + q * 4;
#pragma unroll
        for (int it = 0; it < 4; ++it) {
            const int i = i0 + it * 16 + ln;
#pragma unroll
            for (int r = 0; r < 4; ++r) {
                const size_t idx = ((size_t)(b * CC + c + r)) * LL + i;
                out[idx] = g * (oacc[ct][it][r] * linv[it]) + x[idx];
            }
        }
    }
}

// ---------------- launcher ----------------
extern "C" void kernel_launch(void* const* d_in, const int* in_sizes, int n_in,
                              void* d_out, int out_size, void* d_ws, size_t ws_size,
                              hipStream_t stream)
{
    const float* x     = (const float*)d_in[0];
    const float* Wq    = (const float*)d_in[1];
    const float* bq    = (const float*)d_in[2];
    const float* Wk    = (const float*)d_in[3];
    const float* bk    = (const float*)d_in[4];
    const float* Wv    = (const float*)d_in[5];
    const float* bv    = (const float*)d_in[6];
    const float* gamma = (const float*)d_in[7];
    float* out = (float*)d_out;

    uint8_t* ws = (uint8_t*)d_ws;
    u16* Wh  = (u16*)(ws + 0x000000);
    u16* xt  = (u16*)(ws + 0x040000);
    u16* Qh  = (u16*)(ws + 0x840000);
    u16* Kth = (u16*)(ws + 0x940000);
    u16* Vh  = (u16*)(ws + 0xA40000);

    prep_w_kernel<<<80, 256, 0, stream>>>(Wq, Wk, Wv, Wh);
    prep_xt_kernel<<<1024, 256, 0, stream>>>(x, xt);
    proj_kernel<<<1024, 256, 0, stream>>>(xt, Wh, bq, bk, bv, Qh, Kth, Vh);
    attn_kernel<<<256, 512, 0, stream>>>(Qh, Kth, Vh, x, gamma, out);
}

// Round 4
// 148.899 us; speedup vs baseline: 1.1422x; 1.0571x over previous
//
#include <hip/hip_runtime.h>
#include <stdint.h>

// SelfAttention1D: B=8, C=256, L=2048, D=32, fp32 in/out, bf16 MFMA compute.
//
// ws layout (bytes):
//   Wh  @ 0x000000 : bf16 [320][256]   rows 0-31 Wq, 32-63 Wk, 64-319 Wv (160 KB)
//   Qh  @ 0x040000 : bf16 [B][L][32]   Q pre-scaled by (1/sqrt(D))*log2(e) (1 MB)
//   Kth @ 0x140000 : bf16 [B][L][32]   K^T, d-contiguous (1 MB)
//   Vh  @ 0x240000 : bf16 [B][256][L]  V, j-contiguous (8 MB)
// total 10.25 MB

#define BB 8
#define CC 256
#define LL 2048
#define DD 32

typedef unsigned short u16;
typedef __attribute__((ext_vector_type(8))) short short8;
typedef __attribute__((ext_vector_type(4))) float f32x4;

#define SCALE_LOG2E 0.2550348612f

static __device__ __forceinline__ uint32_t pack2bf16(float hi, float lo) {
    return (__float_as_uint(hi) & 0xFFFF0000u) | (__float_as_uint(lo) >> 16);
}

static __device__ __forceinline__ float fexp2(float v) {
#if __has_builtin(__builtin_amdgcn_exp2f)
    return __builtin_amdgcn_exp2f(v);
#else
    return exp2f(v);
#endif
}

static __device__ __forceinline__ float frcp(float v) {
#if __has_builtin(__builtin_amdgcn_rcpf)
    return __builtin_amdgcn_rcpf(v);
#else
    return 1.0f / v;
#endif
}

// ---------------- kernel 1: W -> bf16 ----------------
__global__ __launch_bounds__(256) void prep_w_kernel(
    const float* __restrict__ Wq, const float* __restrict__ Wk,
    const float* __restrict__ Wv, u16* __restrict__ Wh)
{
    int idx = blockIdx.x * 256 + threadIdx.x;     // 320 rows * 64 float4
    int r = idx >> 6;
    int c4 = (idx & 63) << 2;
    const float* src;
    if (r < 32)       src = Wq + (size_t)r * CC + c4;
    else if (r < 64)  src = Wk + (size_t)(r - 32) * CC + c4;
    else              src = Wv + (size_t)(r - 64) * CC + c4;
    float4 v = *(const float4*)src;
    uint2 o;
    o.x = pack2bf16(v.y, v.x);
    o.y = pack2bf16(v.w, v.z);
    *(uint2*)(Wh + (size_t)r * CC + c4) = o;
}

// ---------------- kernel 2: QKV projection ----------------
// grid 512 = 8 b x 64 l-tiles(32), 512 thr (8 waves), 2 blocks/CU.
// Stage x[256 c][32 l] -> LDS transposed bf16 xls[32 l][264] (coalesced
// float4 reads; one-time scalar bf16 writes). Wave (wl = w&1 -> 16 l,
// wm = w>>1 -> 80 m-rows): B-frags = contiguous b128 from xls, A-frags =
// contiguous 16B from Wh (L1/L2).
__global__ __launch_bounds__(512, 2) void proj_kernel(
    const float* __restrict__ x, const u16* __restrict__ Wh,
    const float* __restrict__ bq, const float* __restrict__ bk,
    const float* __restrict__ bv,
    u16* __restrict__ Qh, u16* __restrict__ Kth, u16* __restrict__ Vh)
{
    __shared__ u16 xls[32 * 264];        // 16.9 KB
    const int blk = blockIdx.x;
    const int b = blk & 7;
    const int l0 = (blk >> 3) << 5;
    const int tid = threadIdx.x;
    const int w = tid >> 6;
    const int lane = tid & 63;
    const int ln = lane & 15;
    const int q = lane >> 4;

    // stage: 4 chunks of 64 c-rows; thread -> (c = cc*64 + tid>>3, l4 = (tid&7)*4)
#pragma unroll
    for (int cc = 0; cc < 4; ++cc) {
        const int c = cc * 64 + (tid >> 3);
        const int l4 = (tid & 7) * 4;
        const float4 v = *(const float4*)(x + ((size_t)(b * CC + c)) * LL + l0 + l4);
        xls[(l4 + 0) * 264 + c] = (u16)(__float_as_uint(v.x) >> 16);
        xls[(l4 + 1) * 264 + c] = (u16)(__float_as_uint(v.y) >> 16);
        xls[(l4 + 2) * 264 + c] = (u16)(__float_as_uint(v.z) >> 16);
        xls[(l4 + 3) * 264 + c] = (u16)(__float_as_uint(v.w) >> 16);
    }
    __syncthreads();

    const int wl = w & 1;
    const int wm = w >> 1;               // 0..3 -> 80 rows each
    const int mbase = wm * 80;
    const int l = l0 + wl * 16 + ln;

    f32x4 acc[5];
#pragma unroll
    for (int i = 0; i < 5; ++i) acc[i] = (f32x4){0.f, 0.f, 0.f, 0.f};

#pragma unroll
    for (int c0 = 0; c0 < CC; c0 += 32) {
        const short8 bf = *(const short8*)(&xls[(wl * 16 + ln) * 264 + c0 + q * 8]);
#pragma unroll
        for (int mt = 0; mt < 5; ++mt) {
            const short8 af = *(const short8*)(Wh + (size_t)(mbase + mt * 16 + ln) * CC + c0 + q * 8);
            acc[mt] = __builtin_amdgcn_mfma_f32_16x16x32_bf16(af, bf, acc[mt], 0, 0, 0);
        }
    }

#pragma unroll
    for (int mt = 0; mt < 5; ++mt) {
        const int rg = mbase + mt * 16 + q * 4;   // global output row
        if (rg < 32) {                   // Q rows, pre-scaled
            float v0 = (acc[mt][0] + bq[rg + 0]) * SCALE_LOG2E;
            float v1 = (acc[mt][1] + bq[rg + 1]) * SCALE_LOG2E;
            float v2 = (acc[mt][2] + bq[rg + 2]) * SCALE_LOG2E;
            float v3 = (acc[mt][3] + bq[rg + 3]) * SCALE_LOG2E;
            uint2 o; o.x = pack2bf16(v1, v0); o.y = pack2bf16(v3, v2);
            *(uint2*)(Qh + ((size_t)(b * LL) + l) * DD + rg) = o;
        } else if (rg < 64) {            // K rows
            const int rk = rg - 32;
            float v0 = acc[mt][0] + bk[rk + 0];
            float v1 = acc[mt][1] + bk[rk + 1];
            float v2 = acc[mt][2] + bk[rk + 2];
            float v3 = acc[mt][3] + bk[rk + 3];
            uint2 o; o.x = pack2bf16(v1, v0); o.y = pack2bf16(v3, v2);
            *(uint2*)(Kth + ((size_t)(b * LL) + l) * DD + rk) = o;
        } else {                         // V rows -> Vh[b][c][l]
            const int cv = rg - 64;
#pragma unroll
            for (int rr = 0; rr < 4; ++rr) {
                const float v = acc[mt][rr] + bv[cv + rr];
                Vh[((size_t)(b * CC) + cv + rr) * LL + l] = (u16)(__float_as_uint(v) >> 16);
            }
        }
    }
}

// ---------------- kernel 3: fused attention (barrier-free main loop) ----------------
// grid 256 = (b = blk&7 -> XCD L2 affinity) x (i-tile 64). 512 thr (8 waves):
// wc = w>>2 (c-half 128), wj = w&3 (j-slices jb = n*128 + wj*32, n=0..15).
// Each wave independently: S^T = K.Q^T (8 MFMA) -> exp2 -> P via wave-PRIVATE
// LDS (C->B layout transform; no __syncthreads) -> O^T += V.P^T (32 MFMA).
// V loads issue at iter top, consumed after the ~500-cyc S phase (hides L2
// latency); K prefetched one iter ahead. l accumulated in-register. Epilogue:
// O reduced over wj via 4 barriered LDS passes, coalesced float4 finalize.
__global__ __launch_bounds__(512, 1) void attn_kernel(
    const u16* __restrict__ Qh, const u16* __restrict__ Kth,
    const u16* __restrict__ Vh, const float* __restrict__ x,
    const float* __restrict__ gamma, float* __restrict__ out)
{
    __shared__ u16 pbuf[8 * 64 * 40];    // wave-private P: 40 KB
    __shared__ float obuf[256 * 68];     // 69.6 KB
    __shared__ float lbuf[8 * 64];       // 2 KB

    const int blk = blockIdx.x;
    const int b = blk & 7;
    const int i0 = (blk >> 3) << 6;
    const int tid = threadIdx.x;
    const int w = tid >> 6;              // 0..7
    const int wc = w >> 2;               // 0..1
    const int wj = w & 3;                // 0..3
    const int lane = tid & 63;
    const int ln = lane & 15;
    const int q = lane >> 4;

    u16* pb = pbuf + w * (64 * 40);
    const u16* Qb = Qh + ((size_t)(b * LL) + i0) * DD;
    const u16* Kb = Kth + (size_t)(b * LL) * DD;
    const u16* Vb = Vh + ((size_t)(b * CC) + wc * 128) * LL;

    short8 qf[4];
#pragma unroll
    for (int it = 0; it < 4; ++it)
        qf[it] = *(const short8*)(Qb + (size_t)(it * 16 + ln) * DD + q * 8);

    const f32x4 zf = {0.f, 0.f, 0.f, 0.f};
    f32x4 oacc[8][4];                    // [ct][it] = 128 VGPRs
#pragma unroll
    for (int a = 0; a < 8; ++a)
#pragma unroll
        for (int c = 0; c < 4; ++c) oacc[a][c] = zf;
    float lsum[4] = {0.f, 0.f, 0.f, 0.f};

    // K prefetch for iter 0
    int jb = wj * 32;
    short8 kf0 = *(const short8*)(Kb + (size_t)(jb + ln) * DD + q * 8);
    short8 kf1 = *(const short8*)(Kb + (size_t)(jb + 16 + ln) * DD + q * 8);

    for (int n = 0; n < 16; ++n) {
        jb = n * 128 + wj * 32;
        const int jnx = (n < 15) ? (n + 1) * 128 + wj * 32 : jb;

        // V loads for THIS iter (consumed after S phase -> latency hidden)
        short8 vf[8];
#pragma unroll
        for (int ct = 0; ct < 8; ++ct)
            vf[ct] = *(const short8*)(Vb + (size_t)(ct * 16 + ln) * LL + jb + q * 8);
        // K prefetch for next iter
        const short8 kn0 = *(const short8*)(Kb + (size_t)(jnx + ln) * DD + q * 8);
        const short8 kn1 = *(const short8*)(Kb + (size_t)(jnx + 16 + ln) * DD + q * 8);

        // ---- S phase: S^T = K.Q^T (32 j x 64 i), exp2, P -> private LDS ----
#pragma unroll
        for (int jt = 0; jt < 2; ++jt) {
            const short8 kf = jt ? kf1 : kf0;
#pragma unroll
            for (int it = 0; it < 4; ++it) {
                const f32x4 st = __builtin_amdgcn_mfma_f32_16x16x32_bf16(kf, qf[it], zf, 0, 0, 0);
                const float e0 = fexp2(st[0]), e1 = fexp2(st[1]);
                const float e2 = fexp2(st[2]), e3 = fexp2(st[3]);
                lsum[it] += (e0 + e1) + (e2 + e3);
                uint2 d; d.x = pack2bf16(e1, e0); d.y = pack2bf16(e3, e2);
                *(uint2*)(&pb[(it * 16 + ln) * 40 + jt * 16 + q * 4]) = d;
            }
        }

        // ---- read back as B-frags (same wave; compiler emits lgkmcnt wait) ----
        short8 pf[4];
#pragma unroll
        for (int it = 0; it < 4; ++it)
            pf[it] = *(const short8*)(&pb[(it * 16 + ln) * 40 + q * 8]);

        // ---- PV: O^T += V.P^T over exclusive 128-c half ----
#pragma unroll
        for (int ct = 0; ct < 8; ++ct)
#pragma unroll
            for (int it = 0; it < 4; ++it)
                oacc[ct][it] = __builtin_amdgcn_mfma_f32_16x16x32_bf16(vf[ct], pf[it], oacc[ct][it], 0, 0, 0);

        kf0 = kn0; kf1 = kn1;
    }

    // ---- l: reduce over q within wave; publish per-wave partials ----
#pragma unroll
    for (int it = 0; it < 4; ++it) {
        float s = lsum[it];
        s += __shfl_xor(s, 16);
        s += __shfl_xor(s, 32);
        lsum[it] = s;
    }
    if (q == 0) {
#pragma unroll
        for (int it = 0; it < 4; ++it) lbuf[w * 64 + it * 16 + ln] = lsum[it];
    }

    // ---- O reduction over wj (4 serialized passes, disjoint c across wc) ----
#pragma unroll
    for (int p = 0; p < 4; ++p) {
        if (wj == p) {
#pragma unroll
            for (int ct = 0; ct < 8; ++ct)
#pragma unroll
                for (int it = 0; it < 4; ++it) {
                    const int i = it * 16 + ln;
#pragma unroll
                    for (int r = 0; r < 4; ++r) {
                        const int c = wc * 128 + ct * 16 + q * 4 + r;
                        if (p == 0) obuf[c * 68 + i] = oacc[ct][it][r];
                        else        obuf[c * 68 + i] += oacc[ct][it][r];
                    }
                }
        }
        __syncthreads();
    }

    // ---- finalize: out = gamma * O/l + x (coalesced float4) ----
    // lbuf summed over all 8 waves double-counts l (2 wc duplicates) -> 2/s.
    const float g = gamma[0];
    const int i4 = (tid & 15) * 4;
    float4 sv = {0.f, 0.f, 0.f, 0.f};
#pragma unroll
    for (int ww = 0; ww < 8; ++ww) {
        const float4 lv = *(const float4*)&lbuf[ww * 64 + i4];
        sv.x += lv.x; sv.y += lv.y; sv.z += lv.z; sv.w += lv.w;
    }
    float4 li;
    li.x = 2.0f * frcp(sv.x); li.y = 2.0f * frcp(sv.y);
    li.z = 2.0f * frcp(sv.z); li.w = 2.0f * frcp(sv.w);

#pragma unroll
    for (int cc = 0; cc < 8; ++cc) {
        const int c = cc * 32 + (tid >> 4);
        const float4 ov = *(const float4*)&obuf[c * 68 + i4];
        const size_t idx = ((size_t)(b * CC + c)) * LL + i0 + i4;
        const float4 xv = *(const float4*)(x + idx);
        float4 o;
        o.x = g * (ov.x * li.x) + xv.x;
        o.y = g * (ov.y * li.y) + xv.y;
        o.z = g * (ov.z * li.z) + xv.z;
        o.w = g * (ov.w * li.w) + xv.w;
        *(float4*)(out + idx) = o;
    }
}

// ---------------- launcher ----------------
extern "C" void kernel_launch(void* const* d_in, const int* in_sizes, int n_in,
                              void* d_out, int out_size, void* d_ws, size_t ws_size,
                              hipStream_t stream)
{
    const float* x     = (const float*)d_in[0];
    const float* Wq    = (const float*)d_in[1];
    const float* bq    = (const float*)d_in[2];
    const float* Wk    = (const float*)d_in[3];
    const float* bk    = (const float*)d_in[4];
    const float* Wv    = (const float*)d_in[5];
    const float* bv    = (const float*)d_in[6];
    const float* gamma = (const float*)d_in[7];
    float* out = (float*)d_out;

    uint8_t* ws = (uint8_t*)d_ws;
    u16* Wh  = (u16*)(ws + 0x000000);
    u16* Qh  = (u16*)(ws + 0x040000);
    u16* Kth = (u16*)(ws + 0x140000);
    u16* Vh  = (u16*)(ws + 0x240000);

    prep_w_kernel<<<80, 256, 0, stream>>>(Wq, Wk, Wv, Wh);
    proj_kernel<<<512, 512, 0, stream>>>(x, Wh, bq, bk, bv, Qh, Kth, Vh);
    attn_kernel<<<256, 512, 0, stream>>>(Qh, Kth, Vh, x, gamma, out);
}